// Round 1
// baseline (473.557 us; speedup 1.0000x reference)
//
#include <hip/hip_runtime.h>
#include <hip/hip_bf16.h>
#include <cstdint>
#include <cstddef>

#define DM 2048
#define DG 512
#define NBATCH 4
#define NT 4096
#define NM (NBATCH*NT)     // 16384 rows
#define KC (2*DM)          // 4096 concat-K
#define LN_EPS 1e-5f

typedef __bf16 bf16;
typedef bf16 bf16x8 __attribute__((ext_vector_type(8)));
typedef bf16 bf16x4 __attribute__((ext_vector_type(4)));
typedef float f32x4 __attribute__((ext_vector_type(4)));

// ---------- block-wide sum reduction of two scalars (blockDim.x == 256) ----------
__device__ __forceinline__ void block_reduce_2(float& s, float& s2) {
#pragma unroll
    for (int off = 32; off; off >>= 1) {
        s  += __shfl_down(s, off);
        s2 += __shfl_down(s2, off);
    }
    __shared__ float sm[8];
    const int wid = threadIdx.x >> 6, lane = threadIdx.x & 63;
    if (lane == 0) { sm[wid] = s; sm[4 + wid] = s2; }
    __syncthreads();
    s  = sm[0] + sm[1] + sm[2] + sm[3];
    s2 = sm[4] + sm[5] + sm[6] + sm[7];
}

// ---------- convert f32 -> bf16, 8 elems/thread ----------
__global__ void k_cvt(const float* __restrict__ src, bf16* __restrict__ dst, int n8) {
    int i = blockIdx.x * blockDim.x + threadIdx.x;
    if (i >= n8) return;
    const f32x4* s = (const f32x4*)src + (size_t)i * 2;
    f32x4 a = s[0], b = s[1];
    bf16x8 o;
    o[0] = (bf16)a[0]; o[1] = (bf16)a[1]; o[2] = (bf16)a[2]; o[3] = (bf16)a[3];
    o[4] = (bf16)b[0]; o[5] = (bf16)b[1]; o[6] = (bf16)b[2]; o[7] = (bf16)b[3];
    *((bf16x8*)dst + i) = o;
}

// ---------- small GEMV: out[b][j] = dot(X[b,:K], W[j,:K]) + bias[j]; one wave per j, all 4 batches ----------
template<int K>
__global__ void k_dot(const float* __restrict__ X, const float* __restrict__ W,
                      const float* __restrict__ bias, float* __restrict__ out) {
    const int lane = threadIdx.x & 63;
    const int wid  = threadIdx.x >> 6;
    const int j = blockIdx.x * 4 + wid;
    const f32x4* Wr = (const f32x4*)(W + (size_t)j * K);
    float acc[NBATCH] = {0.f, 0.f, 0.f, 0.f};
    constexpr int C = K / 4 / 64;   // f32x4 chunks per lane
#pragma unroll
    for (int i = 0; i < C; i++) {
        f32x4 wv = Wr[lane + 64 * i];
#pragma unroll
        for (int b = 0; b < NBATCH; b++) {
            f32x4 xv = ((const f32x4*)(X + (size_t)b * K))[lane + 64 * i];
            acc[b] += wv[0]*xv[0] + wv[1]*xv[1] + wv[2]*xv[2] + wv[3]*xv[3];
        }
    }
#pragma unroll
    for (int off = 32; off; off >>= 1)
#pragma unroll
        for (int b = 0; b < NBATCH; b++) acc[b] += __shfl_down(acc[b], off);
    if (lane == 0) {
        const float bb = bias[j];
#pragma unroll
        for (int b = 0; b < NBATCH; b++) out[(size_t)b * DM + j] = acc[b] + bb;
    }
}

// ---------- LN over rows of [NBATCH][DM] ----------
__global__ void k_ln_small(const float* __restrict__ in, const float* __restrict__ g,
                           const float* __restrict__ bt, float* __restrict__ out) {
    const int row = blockIdx.x;
    const int tid = threadIdx.x;
    const f32x4* ir = (const f32x4*)(in + (size_t)row * DM);
    f32x4 v0 = ir[tid], v1 = ir[tid + 256];
    float s  = v0[0]+v0[1]+v0[2]+v0[3] + v1[0]+v1[1]+v1[2]+v1[3];
    float s2 = v0[0]*v0[0]+v0[1]*v0[1]+v0[2]*v0[2]+v0[3]*v0[3]
             + v1[0]*v1[0]+v1[1]*v1[1]+v1[2]*v1[2]+v1[3]*v1[3];
    block_reduce_2(s, s2);
    const float mu = s * (1.0f / DM);
    const float r  = rsqrtf(s2 * (1.0f / DM) - mu * mu + LN_EPS);
    f32x4 g0 = ((const f32x4*)g)[tid],  g1v = ((const f32x4*)g)[tid + 256];
    f32x4 b0 = ((const f32x4*)bt)[tid], b1v = ((const f32x4*)bt)[tid + 256];
    f32x4 o0 = (v0 - mu) * r * g0 + b0;
    f32x4 o1 = (v1 - mu) * r * g1v + b1v;
    f32x4* orow = (f32x4*)(out + (size_t)row * DM);
    orow[tid] = o0; orow[tid + 256] = o1;
}

// ---------- per-row stats of (h+attn), pack bf16 [h | attn_out] ----------
__global__ void k_stats_pack(const float* __restrict__ h, const float* __restrict__ attnv,
                             const float* __restrict__ g2, const float* __restrict__ b2,
                             bf16* __restrict__ Acat, float* __restrict__ muA, float* __restrict__ rA) {
    const int m = blockIdx.x;
    const int b = m >> 12;           // m / NT
    const int tid = threadIdx.x;
    const f32x4* hr = (const f32x4*)(h + (size_t)m * DM);
    const f32x4* ar = (const f32x4*)(attnv + (size_t)b * DM);
    f32x4 h0 = hr[tid], h1 = hr[tid + 256];
    f32x4 a0 = ar[tid], a1 = ar[tid + 256];
    f32x4 x0 = h0 + a0, x1 = h1 + a1;
    float s  = x0[0]+x0[1]+x0[2]+x0[3] + x1[0]+x1[1]+x1[2]+x1[3];
    float s2 = x0[0]*x0[0]+x0[1]*x0[1]+x0[2]*x0[2]+x0[3]*x0[3]
             + x1[0]*x1[0]+x1[1]*x1[1]+x1[2]*x1[2]+x1[3]*x1[3];
    block_reduce_2(s, s2);
    const float mu = s * (1.0f / DM);
    const float r  = rsqrtf(s2 * (1.0f / DM) - mu * mu + LN_EPS);
    if (tid == 0) { muA[m] = mu; rA[m] = r; }
    f32x4 gg0 = ((const f32x4*)g2)[tid], gg1 = ((const f32x4*)g2)[tid + 256];
    f32x4 bb0 = ((const f32x4*)b2)[tid], bb1 = ((const f32x4*)b2)[tid + 256];
    f32x4 ao0 = (x0 - mu) * r * gg0 + bb0;
    f32x4 ao1 = (x1 - mu) * r * gg1 + bb1;
    bf16* row = Acat + (size_t)m * KC;
    bf16x4 w;
    w[0]=(bf16)h0[0]; w[1]=(bf16)h0[1]; w[2]=(bf16)h0[2]; w[3]=(bf16)h0[3];
    *(bf16x4*)&row[4*tid] = w;
    w[0]=(bf16)h1[0]; w[1]=(bf16)h1[1]; w[2]=(bf16)h1[2]; w[3]=(bf16)h1[3];
    *(bf16x4*)&row[4*(tid+256)] = w;
    w[0]=(bf16)ao0[0]; w[1]=(bf16)ao0[1]; w[2]=(bf16)ao0[2]; w[3]=(bf16)ao0[3];
    *(bf16x4*)&row[DM + 4*tid] = w;
    w[0]=(bf16)ao1[0]; w[1]=(bf16)ao1[1]; w[2]=(bf16)ao1[2]; w[3]=(bf16)ao1[3];
    *(bf16x4*)&row[DM + 4*(tid+256)] = w;
}

// ---------- 128x128 bf16 MFMA GEMM (B^T layout): gl = Acat @ Wg^T + b_gate ----------
__global__ __launch_bounds__(256) void k_gemm(const bf16* __restrict__ A, const bf16* __restrict__ Bw,
                                              const float* __restrict__ bgate, bf16* __restrict__ gl) {
    __shared__ bf16 As[128 * 32];
    __shared__ bf16 Bs[128 * 32];
    const int tid  = threadIdx.x;
    const int lane = tid & 63;
    const int wid  = tid >> 6;
    const int bm = blockIdx.y * 128;
    const int bn = blockIdx.x * 128;
    const int wm = wid >> 1, wn = wid & 1;
    f32x4 acc[4][4] = {};
    // staging: thread t covers LDS bytes [t*16) and [4096 + t*16) of each 8KB tile
    const int r0 = tid >> 2;              // row (32 bf16 = 64B per row, 4 threads/row)
    const int c0 = (tid & 3) << 3;        // col element
    auto As3 = (__attribute__((address_space(3))) char*)As + (wid << 10);
    auto Bs3 = (__attribute__((address_space(3))) char*)Bs + (wid << 10);
    const bf16* Ag0 = A  + (size_t)(bm + r0) * KC + c0;
    const bf16* Bg0 = Bw + (size_t)(bn + r0) * KC + c0;
    const int arow = (wm << 6) + (lane & 15);
    const int brow = (wn << 6) + (lane & 15);
    const int kc   = (lane >> 4) << 3;
    for (int kt = 0; kt < KC; kt += 32) {
        const bf16* Ag = Ag0 + kt;
        const bf16* Bg = Bg0 + kt;
        __builtin_amdgcn_global_load_lds((const __attribute__((address_space(1))) void*)Ag,
                                         (__attribute__((address_space(3))) void*)As3,          16, 0, 0);
        __builtin_amdgcn_global_load_lds((const __attribute__((address_space(1))) void*)(Ag + 64 * KC),
                                         (__attribute__((address_space(3))) void*)(As3 + 4096), 16, 0, 0);
        __builtin_amdgcn_global_load_lds((const __attribute__((address_space(1))) void*)Bg,
                                         (__attribute__((address_space(3))) void*)Bs3,          16, 0, 0);
        __builtin_amdgcn_global_load_lds((const __attribute__((address_space(1))) void*)(Bg + 64 * KC),
                                         (__attribute__((address_space(3))) void*)(Bs3 + 4096), 16, 0, 0);
        asm volatile("s_waitcnt vmcnt(0)" ::: "memory");
        __syncthreads();
        bf16x8 af[4], bfr[4];
#pragma unroll
        for (int f = 0; f < 4; f++) {
            af[f]  = *(const bf16x8*)&As[(arow + f * 16) * 32 + kc];
            bfr[f] = *(const bf16x8*)&Bs[(brow + f * 16) * 32 + kc];
        }
#pragma unroll
        for (int fm = 0; fm < 4; fm++)
#pragma unroll
            for (int fn = 0; fn < 4; fn++)
                acc[fm][fn] = __builtin_amdgcn_mfma_f32_16x16x32_bf16(af[fm], bfr[fn], acc[fm][fn], 0, 0, 0);
        __syncthreads();
    }
    const int row0 = bm + (wm << 6) + ((lane >> 4) << 2);
    const int col0 = bn + (wn << 6) + (lane & 15);
#pragma unroll
    for (int fn = 0; fn < 4; fn++) {
        const int col = col0 + fn * 16;
        const float bg = bgate[col];
#pragma unroll
        for (int fm = 0; fm < 4; fm++) {
#pragma unroll
            for (int r = 0; r < 4; r++) {
                gl[(size_t)(row0 + fm * 16 + r) * DM + col] = (bf16)(acc[fm][fn][r] + bg);
            }
        }
    }
}

// ---------- epilogue: gate/fuse/LN3 per row ----------
__global__ void k_epilogue(const float* __restrict__ h, const bf16* __restrict__ gl,
                           const float* __restrict__ attnv, const float* __restrict__ muA,
                           const float* __restrict__ rA,
                           const float* __restrict__ g2, const float* __restrict__ b2,
                           const float* __restrict__ g3, const float* __restrict__ b3,
                           float* __restrict__ out) {
    const int m = blockIdx.x;
    const int b = m >> 12;
    const int tid = threadIdx.x;
    const f32x4* hr = (const f32x4*)(h + (size_t)m * DM);
    const f32x4* ar = (const f32x4*)(attnv + (size_t)b * DM);
    f32x4 h0 = hr[tid], h1 = hr[tid + 256];
    f32x4 a0 = ar[tid], a1 = ar[tid + 256];
    const float mu = muA[m];
    const float r  = rA[m];
    f32x4 gg0 = ((const f32x4*)g2)[tid], gg1 = ((const f32x4*)g2)[tid + 256];
    f32x4 bb0 = ((const f32x4*)b2)[tid], bb1 = ((const f32x4*)b2)[tid + 256];
    f32x4 ao0 = (h0 + a0 - mu) * r * gg0 + bb0;
    f32x4 ao1 = (h1 + a1 - mu) * r * gg1 + bb1;
    bf16x4 q0 = *(const bf16x4*)&gl[(size_t)m * DM + 4 * tid];
    bf16x4 q1 = *(const bf16x4*)&gl[(size_t)m * DM + 4 * (tid + 256)];
    f32x4 z0, z1;
#pragma unroll
    for (int q = 0; q < 4; q++) { z0[q] = (float)q0[q]; z1[q] = (float)q1[q]; }
    f32x4 gt0, gt1;
#pragma unroll
    for (int q = 0; q < 4; q++) {
        gt0[q] = 1.0f / (1.0f + __expf(-z0[q]));
        gt1[q] = 1.0f / (1.0f + __expf(-z1[q]));
    }
    f32x4 f0 = h0 + gt0 * (ao0 - h0);
    f32x4 f1 = h1 + gt1 * (ao1 - h1);
    float s  = f0[0]+f0[1]+f0[2]+f0[3] + f1[0]+f1[1]+f1[2]+f1[3];
    float s2 = f0[0]*f0[0]+f0[1]*f0[1]+f0[2]*f0[2]+f0[3]*f0[3]
             + f1[0]*f1[0]+f1[1]*f1[1]+f1[2]*f1[2]+f1[3]*f1[3];
    block_reduce_2(s, s2);
    const float mu3 = s * (1.0f / DM);
    const float r3  = rsqrtf(s2 * (1.0f / DM) - mu3 * mu3 + LN_EPS);
    f32x4 g30 = ((const f32x4*)g3)[tid], g31 = ((const f32x4*)g3)[tid + 256];
    f32x4 b30 = ((const f32x4*)b3)[tid], b31 = ((const f32x4*)b3)[tid + 256];
    f32x4 o0 = (f0 - mu3) * r3 * g30 + b30;
    f32x4 o1 = (f1 - mu3) * r3 * g31 + b31;
    f32x4* orow = (f32x4*)(out + (size_t)m * DM);
    orow[tid] = o0; orow[tid + 256] = o1;
}

extern "C" void kernel_launch(void* const* d_in, const int* in_sizes, int n_in,
                              void* d_out, int out_size, void* d_ws, size_t ws_size,
                              hipStream_t stream) {
    const float* h_llm    = (const float*)d_in[0];
    const float* h_change = (const float*)d_in[1];
    const float* w_proj   = (const float*)d_in[2];
    const float* b_proj   = (const float*)d_in[3];
    const float* g1       = (const float*)d_in[4];
    const float* b1       = (const float*)d_in[5];
    const float* w_v      = (const float*)d_in[6];
    const float* b_v      = (const float*)d_in[7];
    const float* w_o      = (const float*)d_in[8];
    const float* b_o      = (const float*)d_in[9];
    const float* g2       = (const float*)d_in[10];
    const float* b2       = (const float*)d_in[11];
    const float* w_gate   = (const float*)d_in[12];
    const float* b_gate   = (const float*)d_in[13];
    const float* g3       = (const float*)d_in[14];
    const float* b3       = (const float*)d_in[15];
    float* out = (float*)d_out;

    char* ws = (char*)d_ws;
    bf16* Acat = (bf16*)ws;   ws += (size_t)NM * KC * 2;       // 134.2 MB
    bf16* wgb  = (bf16*)ws;   ws += (size_t)DM * KC * 2;       // 16.8 MB
    bf16* gl   = (bf16*)ws;   ws += (size_t)NM * DM * 2;       // 67.1 MB
    float* muA = (float*)ws;  ws += (size_t)NM * 4;
    float* rA  = (float*)ws;  ws += (size_t)NM * 4;
    float* raw1 = (float*)ws; ws += (size_t)NBATCH * DM * 4;
    float* hc   = (float*)ws; ws += (size_t)NBATCH * DM * 4;
    float* raw2 = (float*)ws; ws += (size_t)NBATCH * DM * 4;
    float* attnv= (float*)ws; ws += (size_t)NBATCH * DM * 4;

    // weight convert (independent of the small chain)
    k_cvt<<<(DM * KC / 8 + 255) / 256, 256, 0, stream>>>(w_gate, wgb, DM * KC / 8);
    // small chain: hc = LN(h_change @ w_proj^T + b_proj); attn = (hc @ w_v^T + b_v) @ w_o^T + b_o
    k_dot<DG><<<DM / 4, 256, 0, stream>>>(h_change, w_proj, b_proj, raw1);
    k_ln_small<<<NBATCH, 256, 0, stream>>>(raw1, g1, b1, hc);
    k_dot<DM><<<DM / 4, 256, 0, stream>>>(hc, w_v, b_v, raw2);
    k_dot<DM><<<DM / 4, 256, 0, stream>>>(raw2, w_o, b_o, attnv);
    // row stats + bf16 pack [h | attn_out]
    k_stats_pack<<<NM, 256, 0, stream>>>(h_llm, attnv, g2, b2, Acat, muA, rA);
    // big GEMM: gate logits
    dim3 gC(DM / 128, NM / 128);
    k_gemm<<<gC, 256, 0, stream>>>(Acat, wgb, b_gate, gl);
    // epilogue: sigmoid gate, fuse, LN3
    k_epilogue<<<NM, 256, 0, stream>>>(h_llm, gl, attnv, muA, rA, g2, b2, g3, b3, out);
}

// Round 2
// 380.067 us; speedup vs baseline: 1.2460x; 1.2460x over previous
//
#include <hip/hip_runtime.h>
#include <hip/hip_bf16.h>
#include <cstdint>
#include <cstddef>

#define DM 2048
#define DG 512
#define NBATCH 4
#define NT 4096
#define NM (NBATCH*NT)     // 16384 rows
#define KC (2*DM)          // 4096 concat-K
#define LN_EPS 1e-5f
#define NTILES (KC/64)     // 64 K-tiles of BK=64

typedef __bf16 bf16;
typedef bf16 bf16x8 __attribute__((ext_vector_type(8)));
typedef bf16 bf16x4 __attribute__((ext_vector_type(4)));
typedef float f32x4 __attribute__((ext_vector_type(4)));

#define AS1 __attribute__((address_space(1)))
#define AS3 __attribute__((address_space(3)))

// ---------- block-wide sum reduction of two scalars (blockDim.x == 256) ----------
__device__ __forceinline__ void block_reduce_2(float& s, float& s2) {
#pragma unroll
    for (int off = 32; off; off >>= 1) {
        s  += __shfl_down(s, off);
        s2 += __shfl_down(s2, off);
    }
    __shared__ float sm[8];
    const int wid = threadIdx.x >> 6, lane = threadIdx.x & 63;
    if (lane == 0) { sm[wid] = s; sm[4 + wid] = s2; }
    __syncthreads();
    s  = sm[0] + sm[1] + sm[2] + sm[3];
    s2 = sm[4] + sm[5] + sm[6] + sm[7];
}

// ---------- convert f32 -> bf16, 8 elems/thread ----------
__global__ void k_cvt(const float* __restrict__ src, bf16* __restrict__ dst, int n8) {
    int i = blockIdx.x * blockDim.x + threadIdx.x;
    if (i >= n8) return;
    const f32x4* s = (const f32x4*)src + (size_t)i * 2;
    f32x4 a = s[0], b = s[1];
    bf16x8 o;
    o[0] = (bf16)a[0]; o[1] = (bf16)a[1]; o[2] = (bf16)a[2]; o[3] = (bf16)a[3];
    o[4] = (bf16)b[0]; o[5] = (bf16)b[1]; o[6] = (bf16)b[2]; o[7] = (bf16)b[3];
    *((bf16x8*)dst + i) = o;
}

// ---------- small GEMV: out[b][j] = dot(X[b,:K], W[j,:K]) + bias[j] ----------
template<int K>
__global__ void k_dot(const float* __restrict__ X, const float* __restrict__ W,
                      const float* __restrict__ bias, float* __restrict__ out) {
    const int lane = threadIdx.x & 63;
    const int wid  = threadIdx.x >> 6;
    const int j = blockIdx.x * 4 + wid;
    const f32x4* Wr = (const f32x4*)(W + (size_t)j * K);
    float acc[NBATCH] = {0.f, 0.f, 0.f, 0.f};
    constexpr int C = K / 4 / 64;
#pragma unroll
    for (int i = 0; i < C; i++) {
        f32x4 wv = Wr[lane + 64 * i];
#pragma unroll
        for (int b = 0; b < NBATCH; b++) {
            f32x4 xv = ((const f32x4*)(X + (size_t)b * K))[lane + 64 * i];
            acc[b] += wv[0]*xv[0] + wv[1]*xv[1] + wv[2]*xv[2] + wv[3]*xv[3];
        }
    }
#pragma unroll
    for (int off = 32; off; off >>= 1)
#pragma unroll
        for (int b = 0; b < NBATCH; b++) acc[b] += __shfl_down(acc[b], off);
    if (lane == 0) {
        const float bb = bias[j];
#pragma unroll
        for (int b = 0; b < NBATCH; b++) out[(size_t)b * DM + j] = acc[b] + bb;
    }
}

// ---------- LN over rows of [NBATCH][DM] ----------
__global__ void k_ln_small(const float* __restrict__ in, const float* __restrict__ g,
                           const float* __restrict__ bt, float* __restrict__ out) {
    const int row = blockIdx.x;
    const int tid = threadIdx.x;
    const f32x4* ir = (const f32x4*)(in + (size_t)row * DM);
    f32x4 v0 = ir[tid], v1 = ir[tid + 256];
    float s  = v0[0]+v0[1]+v0[2]+v0[3] + v1[0]+v1[1]+v1[2]+v1[3];
    float s2 = v0[0]*v0[0]+v0[1]*v0[1]+v0[2]*v0[2]+v0[3]*v0[3]
             + v1[0]*v1[0]+v1[1]*v1[1]+v1[2]*v1[2]+v1[3]*v1[3];
    block_reduce_2(s, s2);
    const float mu = s * (1.0f / DM);
    const float r  = rsqrtf(s2 * (1.0f / DM) - mu * mu + LN_EPS);
    f32x4 g0 = ((const f32x4*)g)[tid],  g1v = ((const f32x4*)g)[tid + 256];
    f32x4 b0 = ((const f32x4*)bt)[tid], b1v = ((const f32x4*)bt)[tid + 256];
    f32x4 o0 = (v0 - mu) * r * g0 + b0;
    f32x4 o1 = (v1 - mu) * r * g1v + b1v;
    f32x4* orow = (f32x4*)(out + (size_t)row * DM);
    orow[tid] = o0; orow[tid + 256] = o1;
}

// ---------- per-row stats of (h+attn), pack bf16 [h | attn_out] ----------
__global__ void k_stats_pack(const float* __restrict__ h, const float* __restrict__ attnv,
                             const float* __restrict__ g2, const float* __restrict__ b2,
                             bf16* __restrict__ Acat, float* __restrict__ muA, float* __restrict__ rA) {
    const int m = blockIdx.x;
    const int b = m >> 12;
    const int tid = threadIdx.x;
    const f32x4* hr = (const f32x4*)(h + (size_t)m * DM);
    const f32x4* ar = (const f32x4*)(attnv + (size_t)b * DM);
    f32x4 h0 = hr[tid], h1 = hr[tid + 256];
    f32x4 a0 = ar[tid], a1 = ar[tid + 256];
    f32x4 x0 = h0 + a0, x1 = h1 + a1;
    float s  = x0[0]+x0[1]+x0[2]+x0[3] + x1[0]+x1[1]+x1[2]+x1[3];
    float s2 = x0[0]*x0[0]+x0[1]*x0[1]+x0[2]*x0[2]+x0[3]*x0[3]
             + x1[0]*x1[0]+x1[1]*x1[1]+x1[2]*x1[2]+x1[3]*x1[3];
    block_reduce_2(s, s2);
    const float mu = s * (1.0f / DM);
    const float r  = rsqrtf(s2 * (1.0f / DM) - mu * mu + LN_EPS);
    if (tid == 0) { muA[m] = mu; rA[m] = r; }
    f32x4 gg0 = ((const f32x4*)g2)[tid], gg1 = ((const f32x4*)g2)[tid + 256];
    f32x4 bb0 = ((const f32x4*)b2)[tid], bb1 = ((const f32x4*)b2)[tid + 256];
    f32x4 ao0 = (x0 - mu) * r * gg0 + bb0;
    f32x4 ao1 = (x1 - mu) * r * gg1 + bb1;
    bf16* row = Acat + (size_t)m * KC;
    bf16x4 w;
    w[0]=(bf16)h0[0]; w[1]=(bf16)h0[1]; w[2]=(bf16)h0[2]; w[3]=(bf16)h0[3];
    *(bf16x4*)&row[4*tid] = w;
    w[0]=(bf16)h1[0]; w[1]=(bf16)h1[1]; w[2]=(bf16)h1[2]; w[3]=(bf16)h1[3];
    *(bf16x4*)&row[4*(tid+256)] = w;
    w[0]=(bf16)ao0[0]; w[1]=(bf16)ao0[1]; w[2]=(bf16)ao0[2]; w[3]=(bf16)ao0[3];
    *(bf16x4*)&row[DM + 4*tid] = w;
    w[0]=(bf16)ao1[0]; w[1]=(bf16)ao1[1]; w[2]=(bf16)ao1[2]; w[3]=(bf16)ao1[3];
    *(bf16x4*)&row[DM + 4*(tid+256)] = w;
}

// ---------- 256x256 8-phase bf16 MFMA GEMM: gl = Acat @ Wg^T + b_gate ----------
// 8 waves (2M x 4N), BK=64, double-buffered 128KB LDS, XOR-swizzled reads,
// counted vmcnt, setprio around MFMA clusters, bijective XCD blockIdx swizzle.
#define MF(a,b,c) __builtin_amdgcn_mfma_f32_16x16x32_bf16(a,b,c,0,0,0)
#define SCHED0() __builtin_amdgcn_sched_barrier(0)
#define BAR()  { SCHED0(); asm volatile("s_barrier" ::: "memory"); SCHED0(); }
#define LGKM0() { asm volatile("s_waitcnt lgkmcnt(0)" ::: "memory"); SCHED0(); }
#define VM(n)  asm volatile("s_waitcnt vmcnt(" #n ")" ::: "memory")

__global__ __launch_bounds__(512, 2) void k_gemm256(const bf16* __restrict__ A, const bf16* __restrict__ Bw,
                                                    const float* __restrict__ bgate, bf16* __restrict__ gl) {
    __shared__ __align__(128) char smem[131072];   // [2 bufs][A 32KB | B 32KB]
    const int tid  = threadIdx.x;
    const int lane = tid & 63;
    const int wid  = tid >> 6;
    const int wm   = wid >> 2, wn = wid & 3;

    // bijective XCD swizzle: 512 blocks, 8 XCDs; chunk = 8 m-panels x 8 n-panels
    const int swz = (blockIdx.x & 7) * 64 + (blockIdx.x >> 3);
    const int bm = (swz >> 3) << 8;
    const int bn = (swz & 7) << 8;

    // ---- staging source pointers (inverse-swizzled global source, linear LDS dest)
    const int r_local = tid >> 3;                 // 0..63 row within a 64-row round
    const int sc = (tid & 7) ^ (r_local & 7);     // swizzled 16B chunk within row
    const bf16* Asrc[4]; const bf16* Bsrc[4];
#pragma unroll
    for (int r = 0; r < 4; r++) {
        Asrc[r] = A  + (size_t)(bm + 64*r + r_local) * KC + sc*8;
        Bsrc[r] = Bw + (size_t)(bn + 64*r + r_local) * KC + sc*8;
    }
    const int ldsW = wid << 10;   // per-wave 1KB slice of each 8KB round

#define STAGEA(buf, rnd, kt) __builtin_amdgcn_global_load_lds( \
        (const AS1 void*)(Asrc[rnd] + (kt)*64), \
        (AS3 void*)(smem + (buf)*65536 + (rnd)*8192 + ldsW), 16, 0, 0)
#define STAGEB(buf, rnd, kt) __builtin_amdgcn_global_load_lds( \
        (const AS1 void*)(Bsrc[rnd] + (kt)*64), \
        (AS3 void*)(smem + (buf)*65536 + 32768 + (rnd)*8192 + ldsW), 16, 0, 0)

    // ---- fragment read offsets (swizzled)
    const int co0 = ((lane >> 4) ^ (lane & 7)) << 4;         // ks=0
    const int co1 = ((4 + (lane >> 4)) ^ (lane & 7)) << 4;   // ks=1
    const int arowb = (wm*128 + (lane & 15)) * 128;          // + m*2048
    const int browb = (wn*64  + (lane & 15)) * 128;          // + n*2048

#define AFRG(buf, m, ks) (*(const bf16x8*)(smem + (buf)*65536 + arowb + (m)*2048 + ((ks) ? co1 : co0)))
#define BFRG(buf, n, ks) (*(const bf16x8*)(smem + (buf)*65536 + 32768 + browb + (n)*2048 + ((ks) ? co1 : co0)))

    f32x4 acc[8][4] = {};
    bf16x8 aF[4][2], b01[2][2], b23[2][2];

    // ---- prologue: tile 0 -> buf0, drain once
#pragma unroll
    for (int r = 0; r < 4; r++) STAGEA(0, r, 0);
#pragma unroll
    for (int r = 0; r < 4; r++) STAGEB(0, r, 0);
    VM(0);
    BAR();

    for (int T = 0; T < NTILES; T++) {
        const int buf = T & 1, nbuf = buf ^ 1;
        const bool g = (T < NTILES - 1);
        // ===== P0: quadrant (m0-3, n0-1); stage next A0,A2
        if (g) { STAGEA(nbuf, 0, T+1); STAGEA(nbuf, 2, T+1); }
#pragma unroll
        for (int i = 0; i < 4; i++) { aF[i][0] = AFRG(buf, i, 0); aF[i][1] = AFRG(buf, i, 1); }
#pragma unroll
        for (int j = 0; j < 2; j++) { b01[j][0] = BFRG(buf, j, 0); b01[j][1] = BFRG(buf, j, 1); }
        BAR(); LGKM0();
        __builtin_amdgcn_s_setprio(1);
#pragma unroll
        for (int i = 0; i < 4; i++)
#pragma unroll
            for (int j = 0; j < 2; j++) {
                acc[i][j] = MF(aF[i][0], b01[j][0], acc[i][j]);
                acc[i][j] = MF(aF[i][1], b01[j][1], acc[i][j]);
            }
        __builtin_amdgcn_s_setprio(0);
        BAR();
        // ===== P1: quadrant (m0-3, n2-3); stage B0,B1; counted vmcnt
        if (g) { STAGEB(nbuf, 0, T+1); STAGEB(nbuf, 1, T+1); }
#pragma unroll
        for (int j = 0; j < 2; j++) { b23[j][0] = BFRG(buf, 2+j, 0); b23[j][1] = BFRG(buf, 2+j, 1); }
        BAR(); LGKM0();
        __builtin_amdgcn_s_setprio(1);
#pragma unroll
        for (int i = 0; i < 4; i++)
#pragma unroll
            for (int j = 0; j < 2; j++) {
                acc[i][2+j] = MF(aF[i][0], b23[j][0], acc[i][2+j]);
                acc[i][2+j] = MF(aF[i][1], b23[j][1], acc[i][2+j]);
            }
        __builtin_amdgcn_s_setprio(0);
        if (g) { VM(4); } else { VM(0); }   // tile's A1,A3 must be landed for P2
        BAR();
        // ===== P2: quadrant (m4-7, n2-3); stage B2,B3
        if (g) { STAGEB(nbuf, 2, T+1); STAGEB(nbuf, 3, T+1); }
#pragma unroll
        for (int i = 0; i < 4; i++) { aF[i][0] = AFRG(buf, 4+i, 0); aF[i][1] = AFRG(buf, 4+i, 1); }
        BAR(); LGKM0();
        __builtin_amdgcn_s_setprio(1);
#pragma unroll
        for (int i = 0; i < 4; i++)
#pragma unroll
            for (int j = 0; j < 2; j++) {
                acc[4+i][2+j] = MF(aF[i][0], b23[j][0], acc[4+i][2+j]);
                acc[4+i][2+j] = MF(aF[i][1], b23[j][1], acc[4+i][2+j]);
            }
        __builtin_amdgcn_s_setprio(0);
        BAR();
        // ===== P3: quadrant (m4-7, n0-1); stage A1,A3; counted vmcnt
        if (g) { STAGEA(nbuf, 1, T+1); STAGEA(nbuf, 3, T+1); }
#pragma unroll
        for (int j = 0; j < 2; j++) { b01[j][0] = BFRG(buf, j, 0); b01[j][1] = BFRG(buf, j, 1); }
        BAR(); LGKM0();
        __builtin_amdgcn_s_setprio(1);
#pragma unroll
        for (int i = 0; i < 4; i++)
#pragma unroll
            for (int j = 0; j < 2; j++) {
                acc[4+i][j] = MF(aF[i][0], b01[j][0], acc[4+i][j]);
                acc[4+i][j] = MF(aF[i][1], b01[j][1], acc[4+i][j]);
            }
        __builtin_amdgcn_s_setprio(0);
        VM(2);   // next tile's A0,A2,B0-3 landed before its P0 reads
        BAR();
    }

    // ---- epilogue: C = acc + bias -> bf16 gl
#pragma unroll
    for (int n = 0; n < 4; n++) {
        const int col = bn + wn*64 + n*16 + (lane & 15);
        const float bg = bgate[col];
#pragma unroll
        for (int m = 0; m < 8; m++) {
            const int row = bm + wm*128 + m*16 + ((lane >> 4) << 2);
#pragma unroll
            for (int r = 0; r < 4; r++)
                gl[(size_t)(row + r) * DM + col] = (bf16)(acc[m][n][r] + bg);
        }
    }
}

// ---------- epilogue: gate/fuse/LN3 per row ----------
__global__ void k_epilogue(const float* __restrict__ h, const bf16* __restrict__ gl,
                           const float* __restrict__ attnv, const float* __restrict__ muA,
                           const float* __restrict__ rA,
                           const float* __restrict__ g2, const float* __restrict__ b2,
                           const float* __restrict__ g3, const float* __restrict__ b3,
                           float* __restrict__ out) {
    const int m = blockIdx.x;
    const int b = m >> 12;
    const int tid = threadIdx.x;
    const f32x4* hr = (const f32x4*)(h + (size_t)m * DM);
    const f32x4* ar = (const f32x4*)(attnv + (size_t)b * DM);
    f32x4 h0 = hr[tid], h1 = hr[tid + 256];
    f32x4 a0 = ar[tid], a1 = ar[tid + 256];
    const float mu = muA[m];
    const float r  = rA[m];
    f32x4 gg0 = ((const f32x4*)g2)[tid], gg1 = ((const f32x4*)g2)[tid + 256];
    f32x4 bb0 = ((const f32x4*)b2)[tid], bb1 = ((const f32x4*)b2)[tid + 256];
    f32x4 ao0 = (h0 + a0 - mu) * r * gg0 + bb0;
    f32x4 ao1 = (h1 + a1 - mu) * r * gg1 + bb1;
    bf16x4 q0 = *(const bf16x4*)&gl[(size_t)m * DM + 4 * tid];
    bf16x4 q1 = *(const bf16x4*)&gl[(size_t)m * DM + 4 * (tid + 256)];
    f32x4 z0, z1;
#pragma unroll
    for (int q = 0; q < 4; q++) { z0[q] = (float)q0[q]; z1[q] = (float)q1[q]; }
    f32x4 gt0, gt1;
#pragma unroll
    for (int q = 0; q < 4; q++) {
        gt0[q] = 1.0f / (1.0f + __expf(-z0[q]));
        gt1[q] = 1.0f / (1.0f + __expf(-z1[q]));
    }
    f32x4 f0 = h0 + gt0 * (ao0 - h0);
    f32x4 f1 = h1 + gt1 * (ao1 - h1);
    float s  = f0[0]+f0[1]+f0[2]+f0[3] + f1[0]+f1[1]+f1[2]+f1[3];
    float s2 = f0[0]*f0[0]+f0[1]*f0[1]+f0[2]*f0[2]+f0[3]*f0[3]
             + f1[0]*f1[0]+f1[1]*f1[1]+f1[2]*f1[2]+f1[3]*f1[3];
    block_reduce_2(s, s2);
    const float mu3 = s * (1.0f / DM);
    const float r3  = rsqrtf(s2 * (1.0f / DM) - mu3 * mu3 + LN_EPS);
    f32x4 g30 = ((const f32x4*)g3)[tid], g31 = ((const f32x4*)g3)[tid + 256];
    f32x4 b30 = ((const f32x4*)b3)[tid], b31 = ((const f32x4*)b3)[tid + 256];
    f32x4 o0 = (f0 - mu3) * r3 * g30 + b30;
    f32x4 o1 = (f1 - mu3) * r3 * g31 + b31;
    f32x4* orow = (f32x4*)(out + (size_t)m * DM);
    orow[tid] = o0; orow[tid + 256] = o1;
}

extern "C" void kernel_launch(void* const* d_in, const int* in_sizes, int n_in,
                              void* d_out, int out_size, void* d_ws, size_t ws_size,
                              hipStream_t stream) {
    const float* h_llm    = (const float*)d_in[0];
    const float* h_change = (const float*)d_in[1];
    const float* w_proj   = (const float*)d_in[2];
    const float* b_proj   = (const float*)d_in[3];
    const float* g1       = (const float*)d_in[4];
    const float* b1       = (const float*)d_in[5];
    const float* w_v      = (const float*)d_in[6];
    const float* b_v      = (const float*)d_in[7];
    const float* w_o      = (const float*)d_in[8];
    const float* b_o      = (const float*)d_in[9];
    const float* g2       = (const float*)d_in[10];
    const float* b2       = (const float*)d_in[11];
    const float* w_gate   = (const float*)d_in[12];
    const float* b_gate   = (const float*)d_in[13];
    const float* g3       = (const float*)d_in[14];
    const float* b3       = (const float*)d_in[15];
    float* out = (float*)d_out;

    char* ws = (char*)d_ws;
    bf16* Acat = (bf16*)ws;   ws += (size_t)NM * KC * 2;       // 134.2 MB
    bf16* wgb  = (bf16*)ws;   ws += (size_t)DM * KC * 2;       // 16.8 MB
    bf16* gl   = (bf16*)ws;   ws += (size_t)NM * DM * 2;       // 67.1 MB
    float* muA = (float*)ws;  ws += (size_t)NM * 4;
    float* rA  = (float*)ws;  ws += (size_t)NM * 4;
    float* raw1 = (float*)ws; ws += (size_t)NBATCH * DM * 4;
    float* hc   = (float*)ws; ws += (size_t)NBATCH * DM * 4;
    float* raw2 = (float*)ws; ws += (size_t)NBATCH * DM * 4;
    float* attnv= (float*)ws; ws += (size_t)NBATCH * DM * 4;

    k_cvt<<<(DM * KC / 8 + 255) / 256, 256, 0, stream>>>(w_gate, wgb, DM * KC / 8);
    k_dot<DG><<<DM / 4, 256, 0, stream>>>(h_change, w_proj, b_proj, raw1);
    k_ln_small<<<NBATCH, 256, 0, stream>>>(raw1, g1, b1, hc);
    k_dot<DM><<<DM / 4, 256, 0, stream>>>(hc, w_v, b_v, raw2);
    k_dot<DM><<<DM / 4, 256, 0, stream>>>(raw2, w_o, b_o, attnv);
    k_stats_pack<<<NM, 256, 0, stream>>>(h_llm, attnv, g2, b2, Acat, muA, rA);
    k_gemm256<<<512, 512, 0, stream>>>(Acat, wgb, b_gate, gl);
    k_epilogue<<<NM, 256, 0, stream>>>(h_llm, gl, attnv, muA, rA, g2, b2, g3, b3, out);
}

// Round 3
// 377.921 us; speedup vs baseline: 1.2531x; 1.0057x over previous
//
#include <hip/hip_runtime.h>
#include <hip/hip_bf16.h>
#include <cstdint>
#include <cstddef>

#define DM 2048
#define DG 512
#define NBATCH 4
#define NT 4096
#define NM (NBATCH*NT)     // 16384 rows
#define KC (2*DM)          // 4096 concat-K
#define LN_EPS 1e-5f
#define NTILES (KC/64)     // 64 K-tiles of BK=64

typedef __bf16 bf16;
typedef bf16 bf16x8 __attribute__((ext_vector_type(8)));
typedef bf16 bf16x4 __attribute__((ext_vector_type(4)));
typedef float f32x4 __attribute__((ext_vector_type(4)));

#define AS1 __attribute__((address_space(1)))
#define AS3 __attribute__((address_space(3)))

// ---------- block-wide sum reduction of two scalars (blockDim.x == 256) ----------
__device__ __forceinline__ void block_reduce_2(float& s, float& s2) {
#pragma unroll
    for (int off = 32; off; off >>= 1) {
        s  += __shfl_down(s, off);
        s2 += __shfl_down(s2, off);
    }
    __shared__ float sm[8];
    const int wid = threadIdx.x >> 6, lane = threadIdx.x & 63;
    if (lane == 0) { sm[wid] = s; sm[4 + wid] = s2; }
    __syncthreads();
    s  = sm[0] + sm[1] + sm[2] + sm[3];
    s2 = sm[4] + sm[5] + sm[6] + sm[7];
}

// ---------- convert f32 -> bf16, 8 elems/thread ----------
__global__ void k_cvt(const float* __restrict__ src, bf16* __restrict__ dst, int n8) {
    int i = blockIdx.x * blockDim.x + threadIdx.x;
    if (i >= n8) return;
    const f32x4* s = (const f32x4*)src + (size_t)i * 2;
    f32x4 a = s[0], b = s[1];
    bf16x8 o;
    o[0] = (bf16)a[0]; o[1] = (bf16)a[1]; o[2] = (bf16)a[2]; o[3] = (bf16)a[3];
    o[4] = (bf16)b[0]; o[5] = (bf16)b[1]; o[6] = (bf16)b[2]; o[7] = (bf16)b[3];
    *((bf16x8*)dst + i) = o;
}

// ---------- small GEMV: out[b][j] = dot(X[b,:K], W[j,:K]) + bias[j] ----------
template<int K>
__global__ void k_dot(const float* __restrict__ X, const float* __restrict__ W,
                      const float* __restrict__ bias, float* __restrict__ out) {
    const int lane = threadIdx.x & 63;
    const int wid  = threadIdx.x >> 6;
    const int j = blockIdx.x * 4 + wid;
    const f32x4* Wr = (const f32x4*)(W + (size_t)j * K);
    float acc[NBATCH] = {0.f, 0.f, 0.f, 0.f};
    constexpr int C = K / 4 / 64;
#pragma unroll
    for (int i = 0; i < C; i++) {
        f32x4 wv = Wr[lane + 64 * i];
#pragma unroll
        for (int b = 0; b < NBATCH; b++) {
            f32x4 xv = ((const f32x4*)(X + (size_t)b * K))[lane + 64 * i];
            acc[b] += wv[0]*xv[0] + wv[1]*xv[1] + wv[2]*xv[2] + wv[3]*xv[3];
        }
    }
#pragma unroll
    for (int off = 32; off; off >>= 1)
#pragma unroll
        for (int b = 0; b < NBATCH; b++) acc[b] += __shfl_down(acc[b], off);
    if (lane == 0) {
        const float bb = bias[j];
#pragma unroll
        for (int b = 0; b < NBATCH; b++) out[(size_t)b * DM + j] = acc[b] + bb;
    }
}

// ---------- LN over rows of [NBATCH][DM] ----------
__global__ void k_ln_small(const float* __restrict__ in, const float* __restrict__ g,
                           const float* __restrict__ bt, float* __restrict__ out) {
    const int row = blockIdx.x;
    const int tid = threadIdx.x;
    const f32x4* ir = (const f32x4*)(in + (size_t)row * DM);
    f32x4 v0 = ir[tid], v1 = ir[tid + 256];
    float s  = v0[0]+v0[1]+v0[2]+v0[3] + v1[0]+v1[1]+v1[2]+v1[3];
    float s2 = v0[0]*v0[0]+v0[1]*v0[1]+v0[2]*v0[2]+v0[3]*v0[3]
             + v1[0]*v1[0]+v1[1]*v1[1]+v1[2]*v1[2]+v1[3]*v1[3];
    block_reduce_2(s, s2);
    const float mu = s * (1.0f / DM);
    const float r  = rsqrtf(s2 * (1.0f / DM) - mu * mu + LN_EPS);
    f32x4 g0 = ((const f32x4*)g)[tid],  g1v = ((const f32x4*)g)[tid + 256];
    f32x4 b0 = ((const f32x4*)bt)[tid], b1v = ((const f32x4*)bt)[tid + 256];
    f32x4 o0 = (v0 - mu) * r * g0 + b0;
    f32x4 o1 = (v1 - mu) * r * g1v + b1v;
    f32x4* orow = (f32x4*)(out + (size_t)row * DM);
    orow[tid] = o0; orow[tid + 256] = o1;
}

// ---------- per-row stats of (h+attn), pack bf16 [h | attn_out] ----------
__global__ void k_stats_pack(const float* __restrict__ h, const float* __restrict__ attnv,
                             const float* __restrict__ g2, const float* __restrict__ b2,
                             bf16* __restrict__ Acat, float* __restrict__ muA, float* __restrict__ rA) {
    const int m = blockIdx.x;
    const int b = m >> 12;
    const int tid = threadIdx.x;
    const f32x4* hr = (const f32x4*)(h + (size_t)m * DM);
    const f32x4* ar = (const f32x4*)(attnv + (size_t)b * DM);
    f32x4 h0 = hr[tid], h1 = hr[tid + 256];
    f32x4 a0 = ar[tid], a1 = ar[tid + 256];
    f32x4 x0 = h0 + a0, x1 = h1 + a1;
    float s  = x0[0]+x0[1]+x0[2]+x0[3] + x1[0]+x1[1]+x1[2]+x1[3];
    float s2 = x0[0]*x0[0]+x0[1]*x0[1]+x0[2]*x0[2]+x0[3]*x0[3]
             + x1[0]*x1[0]+x1[1]*x1[1]+x1[2]*x1[2]+x1[3]*x1[3];
    block_reduce_2(s, s2);
    const float mu = s * (1.0f / DM);
    const float r  = rsqrtf(s2 * (1.0f / DM) - mu * mu + LN_EPS);
    if (tid == 0) { muA[m] = mu; rA[m] = r; }
    f32x4 gg0 = ((const f32x4*)g2)[tid], gg1 = ((const f32x4*)g2)[tid + 256];
    f32x4 bb0 = ((const f32x4*)b2)[tid], bb1 = ((const f32x4*)b2)[tid + 256];
    f32x4 ao0 = (x0 - mu) * r * gg0 + bb0;
    f32x4 ao1 = (x1 - mu) * r * gg1 + bb1;
    bf16* row = Acat + (size_t)m * KC;
    bf16x4 w;
    w[0]=(bf16)h0[0]; w[1]=(bf16)h0[1]; w[2]=(bf16)h0[2]; w[3]=(bf16)h0[3];
    *(bf16x4*)&row[4*tid] = w;
    w[0]=(bf16)h1[0]; w[1]=(bf16)h1[1]; w[2]=(bf16)h1[2]; w[3]=(bf16)h1[3];
    *(bf16x4*)&row[4*(tid+256)] = w;
    w[0]=(bf16)ao0[0]; w[1]=(bf16)ao0[1]; w[2]=(bf16)ao0[2]; w[3]=(bf16)ao0[3];
    *(bf16x4*)&row[DM + 4*tid] = w;
    w[0]=(bf16)ao1[0]; w[1]=(bf16)ao1[1]; w[2]=(bf16)ao1[2]; w[3]=(bf16)ao1[3];
    *(bf16x4*)&row[DM + 4*(tid+256)] = w;
}

// ---------- 256x256 bf16 MFMA GEMM v3: one-quadrant-ahead register pipeline ----------
// 8 waves (2M x 4N), BK=64, double-buffered 128KB LDS, XOR-swizzled reads,
// ds_reads issued BEFORE the MFMA cluster they don't feed (LDS drains under MFMA),
// 2 barriers/tile, counted vmcnt (never 0 mid-loop), setprio, XCD swizzle.
#define MF(a,b,c) __builtin_amdgcn_mfma_f32_16x16x32_bf16(a,b,c,0,0,0)
#define SCHED0() __builtin_amdgcn_sched_barrier(0)
#define BAR()  { SCHED0(); asm volatile("s_barrier" ::: "memory"); SCHED0(); }
#define VM(n)  asm volatile("s_waitcnt vmcnt(" #n ")" ::: "memory")

__global__ __launch_bounds__(512, 2) void k_gemm256(const bf16* __restrict__ A, const bf16* __restrict__ Bw,
                                                    const float* __restrict__ bgate, bf16* __restrict__ gl) {
    __shared__ __align__(128) char smem[131072];   // [2 bufs][A 32KB | B 32KB]
    const int tid  = threadIdx.x;
    const int lane = tid & 63;
    const int wid  = tid >> 6;
    const int wm   = wid >> 2, wn = wid & 3;

    // bijective XCD swizzle: 512 blocks, 8 XCDs
    const int swz = (blockIdx.x & 7) * 64 + (blockIdx.x >> 3);
    const int bm = (swz >> 3) << 8;
    const int bn = (swz & 7) << 8;

    // staging: lane-part offset + uniform round/kt offsets (saddr-friendly)
    const int r_local = tid >> 3;                 // 0..63 row within a 64-row round
    const int sc = (tid & 7) ^ (r_local & 7);     // inverse-swizzled 16B chunk
    const bf16* Abase = A  + (size_t)(bm + r_local) * KC + sc*8;
    const bf16* Bbase = Bw + (size_t)(bn + r_local) * KC + sc*8;
    const int ldsW = wid << 10;   // per-wave 1KB slice of each 8KB round

#define STAGEA(buf, rnd, kt) __builtin_amdgcn_global_load_lds( \
        (const AS1 void*)(Abase + (size_t)(rnd)*64*KC + (kt)*64), \
        (AS3 void*)(smem + (buf)*65536 + (rnd)*8192 + ldsW), 16, 0, 0)
#define STAGEB(buf, rnd, kt) __builtin_amdgcn_global_load_lds( \
        (const AS1 void*)(Bbase + (size_t)(rnd)*64*KC + (kt)*64), \
        (AS3 void*)(smem + (buf)*65536 + 32768 + (rnd)*8192 + ldsW), 16, 0, 0)

    // fragment read offsets (swizzled)
    const int co0 = ((lane >> 4) ^ (lane & 7)) << 4;         // ks=0
    const int co1 = ((4 + (lane >> 4)) ^ (lane & 7)) << 4;   // ks=1
    const int arowb = (wm*128 + (lane & 15)) * 128;
    const int browb = (wn*64  + (lane & 15)) * 128;

#define AFRG(buf, m, ks) (*(const bf16x8*)(smem + (buf)*65536 + arowb + (m)*2048 + ((ks) ? co1 : co0)))
#define BFRG(buf, n, ks) (*(const bf16x8*)(smem + (buf)*65536 + 32768 + browb + (n)*2048 + ((ks) ? co1 : co0)))

    f32x4 acc[8][4] = {};
    bf16x8 aFa[4][2], aFb[4][2], b01[2][2], b23[2][2];

#define LOAD_AFA(buf) { _Pragma("unroll") for (int i = 0; i < 4; i++) { aFa[i][0] = AFRG(buf,i,0);   aFa[i][1] = AFRG(buf,i,1);   } }
#define LOAD_AFB(buf) { _Pragma("unroll") for (int i = 0; i < 4; i++) { aFb[i][0] = AFRG(buf,4+i,0); aFb[i][1] = AFRG(buf,4+i,1); } }
#define LOAD_B01(buf) { _Pragma("unroll") for (int j = 0; j < 2; j++) { b01[j][0] = BFRG(buf,j,0);   b01[j][1] = BFRG(buf,j,1);   } }
#define LOAD_B23(buf) { _Pragma("unroll") for (int j = 0; j < 2; j++) { b23[j][0] = BFRG(buf,2+j,0); b23[j][1] = BFRG(buf,2+j,1); } }

    // MFMA quadrant: acc[MOFF..MOFF+3][NOFF..NOFF+1] += AF * BF (K=64 via 2 ks)
#define MMQ(MOFF, AF, BF, NOFF) { _Pragma("unroll") for (int i = 0; i < 4; i++) \
        _Pragma("unroll") for (int j = 0; j < 2; j++) { \
            acc[(MOFF)+i][(NOFF)+j] = MF(AF[i][0], BF[j][0], acc[(MOFF)+i][(NOFF)+j]); \
            acc[(MOFF)+i][(NOFF)+j] = MF(AF[i][1], BF[j][1], acc[(MOFF)+i][(NOFF)+j]); } }

    // ---- prologue: tile 0 -> buf0 (order: A0,A2,B0..B3,A1,A3), drain, read Q0 frags
    STAGEA(0,0,0); STAGEA(0,2,0);
    STAGEB(0,0,0); STAGEB(0,1,0); STAGEB(0,2,0); STAGEB(0,3,0);
    STAGEA(0,1,0); STAGEA(0,3,0);
    VM(0);
    BAR();
    LOAD_AFA(0); LOAD_B01(0); SCHED0();

    // quadrants: Q0=(aFa,b01)->acc[0-3][0-1], Q1=(aFb,b01)->acc[4-7][0-1],
    //            Q2=(aFa,b23)->acc[0-3][2-3], Q3=(aFb,b23)->acc[4-7][2-3]
#define TILE_BODY(TT, BUF, NBUF) { \
    const bool g = (TT) < NTILES - 1; \
    /* P0: stage A0,A2(T+1); retire A1,A3(T); issue aFb; MFMA Q0 */ \
    if (g) { STAGEA(NBUF,0,(TT)+1); STAGEA(NBUF,2,(TT)+1); } \
    if (g) { VM(2); } else { VM(0); } \
    BAR(); \
    LOAD_AFB(BUF); SCHED0(); \
    __builtin_amdgcn_s_setprio(1); \
    MMQ(0, aFa, b01, 0); \
    __builtin_amdgcn_s_setprio(0); SCHED0(); \
    /* P1: stage B0,B1(T+1); issue b23; MFMA Q1 */ \
    if (g) { STAGEB(NBUF,0,(TT)+1); STAGEB(NBUF,1,(TT)+1); } \
    LOAD_B23(BUF); SCHED0(); \
    __builtin_amdgcn_s_setprio(1); \
    MMQ(4, aFb, b01, 0); \
    __builtin_amdgcn_s_setprio(0); SCHED0(); \
    /* P2: stage B2,B3(T+1); MFMA Q2 (no new reads) */ \
    if (g) { STAGEB(NBUF,2,(TT)+1); STAGEB(NBUF,3,(TT)+1); } \
    __builtin_amdgcn_s_setprio(1); \
    MMQ(0, aFa, b23, 2); \
    __builtin_amdgcn_s_setprio(0); SCHED0(); \
    /* P3: stage A1,A3(T+1); retire 6; issue Q0-next (aFa,b01 from NBUF); MFMA Q3 */ \
    if (g) { \
        STAGEA(NBUF,1,(TT)+1); STAGEA(NBUF,3,(TT)+1); \
        VM(2); \
        BAR(); \
        LOAD_AFA(NBUF); LOAD_B01(NBUF); SCHED0(); \
    } \
    __builtin_amdgcn_s_setprio(1); \
    MMQ(4, aFb, b23, 2); \
    __builtin_amdgcn_s_setprio(0); SCHED0(); \
}

    for (int T = 0; T < NTILES; T += 2) {
        TILE_BODY(T,   0, 1);
        TILE_BODY(T+1, 1, 0);
    }

    // ---- epilogue: C = acc + bias -> bf16 gl
#pragma unroll
    for (int n = 0; n < 4; n++) {
        const int col = bn + wn*64 + n*16 + (lane & 15);
        const float bg = bgate[col];
#pragma unroll
        for (int m = 0; m < 8; m++) {
            const int row = bm + wm*128 + m*16 + ((lane >> 4) << 2);
#pragma unroll
            for (int r = 0; r < 4; r++)
                gl[(size_t)(row + r) * DM + col] = (bf16)(acc[m][n][r] + bg);
        }
    }
}

// ---------- epilogue: gate/fuse/LN3 per row (h read as bf16 from Acat) ----------
__global__ void k_epilogue(const bf16* __restrict__ Acat, const bf16* __restrict__ gl,
                           const float* __restrict__ attnv, const float* __restrict__ muA,
                           const float* __restrict__ rA,
                           const float* __restrict__ g2, const float* __restrict__ b2,
                           const float* __restrict__ g3, const float* __restrict__ b3,
                           float* __restrict__ out) {
    const int m = blockIdx.x;
    const int b = m >> 12;
    const int tid = threadIdx.x;          // thread handles elems [8*tid, 8*tid+8)
    bf16x8 hb = *(const bf16x8*)(Acat + (size_t)m * KC + 8*tid);
    f32x4 h0, h1;
#pragma unroll
    for (int q = 0; q < 4; q++) { h0[q] = (float)hb[q]; h1[q] = (float)hb[4+q]; }
    const f32x4* ar = (const f32x4*)(attnv + (size_t)b * DM);
    f32x4 a0 = ar[2*tid], a1 = ar[2*tid + 1];
    const float mu = muA[m];
    const float r  = rA[m];
    f32x4 gg0 = ((const f32x4*)g2)[2*tid], gg1 = ((const f32x4*)g2)[2*tid + 1];
    f32x4 bb0 = ((const f32x4*)b2)[2*tid], bb1 = ((const f32x4*)b2)[2*tid + 1];
    f32x4 ao0 = (h0 + a0 - mu) * r * gg0 + bb0;
    f32x4 ao1 = (h1 + a1 - mu) * r * gg1 + bb1;
    bf16x8 qv = *(const bf16x8*)(gl + (size_t)m * DM + 8*tid);
    f32x4 gt0, gt1;
#pragma unroll
    for (int q = 0; q < 4; q++) {
        gt0[q] = 1.0f / (1.0f + __expf(-(float)qv[q]));
        gt1[q] = 1.0f / (1.0f + __expf(-(float)qv[4+q]));
    }
    f32x4 f0 = h0 + gt0 * (ao0 - h0);
    f32x4 f1 = h1 + gt1 * (ao1 - h1);
    float s  = f0[0]+f0[1]+f0[2]+f0[3] + f1[0]+f1[1]+f1[2]+f1[3];
    float s2 = f0[0]*f0[0]+f0[1]*f0[1]+f0[2]*f0[2]+f0[3]*f0[3]
             + f1[0]*f1[0]+f1[1]*f1[1]+f1[2]*f1[2]+f1[3]*f1[3];
    block_reduce_2(s, s2);
    const float mu3 = s * (1.0f / DM);
    const float r3  = rsqrtf(s2 * (1.0f / DM) - mu3 * mu3 + LN_EPS);
    f32x4 g30 = ((const f32x4*)g3)[2*tid], g31 = ((const f32x4*)g3)[2*tid + 1];
    f32x4 b30 = ((const f32x4*)b3)[2*tid], b31 = ((const f32x4*)b3)[2*tid + 1];
    f32x4 o0 = (f0 - mu3) * r3 * g30 + b30;
    f32x4 o1 = (f1 - mu3) * r3 * g31 + b31;
    f32x4* orow = (f32x4*)(out + (size_t)m * DM);
    orow[2*tid] = o0; orow[2*tid + 1] = o1;
}

extern "C" void kernel_launch(void* const* d_in, const int* in_sizes, int n_in,
                              void* d_out, int out_size, void* d_ws, size_t ws_size,
                              hipStream_t stream) {
    const float* h_llm    = (const float*)d_in[0];
    const float* h_change = (const float*)d_in[1];
    const float* w_proj   = (const float*)d_in[2];
    const float* b_proj   = (const float*)d_in[3];
    const float* g1       = (const float*)d_in[4];
    const float* b1       = (const float*)d_in[5];
    const float* w_v      = (const float*)d_in[6];
    const float* b_v      = (const float*)d_in[7];
    const float* w_o      = (const float*)d_in[8];
    const float* b_o      = (const float*)d_in[9];
    const float* g2       = (const float*)d_in[10];
    const float* b2       = (const float*)d_in[11];
    const float* w_gate   = (const float*)d_in[12];
    const float* b_gate   = (const float*)d_in[13];
    const float* g3       = (const float*)d_in[14];
    const float* b3       = (const float*)d_in[15];
    float* out = (float*)d_out;

    char* ws = (char*)d_ws;
    bf16* Acat = (bf16*)ws;   ws += (size_t)NM * KC * 2;       // 134.2 MB
    bf16* wgb  = (bf16*)ws;   ws += (size_t)DM * KC * 2;       // 16.8 MB
    bf16* gl   = (bf16*)ws;   ws += (size_t)NM * DM * 2;       // 67.1 MB
    float* muA = (float*)ws;  ws += (size_t)NM * 4;
    float* rA  = (float*)ws;  ws += (size_t)NM * 4;
    float* raw1 = (float*)ws; ws += (size_t)NBATCH * DM * 4;
    float* hc   = (float*)ws; ws += (size_t)NBATCH * DM * 4;
    float* raw2 = (float*)ws; ws += (size_t)NBATCH * DM * 4;
    float* attnv= (float*)ws; ws += (size_t)NBATCH * DM * 4;

    k_cvt<<<(DM * KC / 8 + 255) / 256, 256, 0, stream>>>(w_gate, wgb, DM * KC / 8);
    k_dot<DG><<<DM / 4, 256, 0, stream>>>(h_change, w_proj, b_proj, raw1);
    k_ln_small<<<NBATCH, 256, 0, stream>>>(raw1, g1, b1, hc);
    k_dot<DM><<<DM / 4, 256, 0, stream>>>(hc, w_v, b_v, raw2);
    k_dot<DM><<<DM / 4, 256, 0, stream>>>(raw2, w_o, b_o, attnv);
    k_stats_pack<<<NM, 256, 0, stream>>>(h_llm, attnv, g2, b2, Acat, muA, rA);
    k_gemm256<<<512, 512, 0, stream>>>(Acat, wgb, b_gate, gl);
    k_epilogue<<<NM, 256, 0, stream>>>(Acat, gl, attnv, muA, rA, g2, b2, g3, b3, out);
}